// Round 6
// baseline (279.232 us; speedup 1.0000x reference)
//
#include <hip/hip_runtime.h>
#include <hip/hip_bf16.h>
#include <cstdint>

#define DEVINL static __device__ __forceinline__

typedef __attribute__((ext_vector_type(4))) float floatx4;
typedef __attribute__((ext_vector_type(8))) short bf16x8;

DEVINL unsigned short f2bf(float f) {
    union { float f; uint32_t u; } v; v.f = f;
    return (unsigned short)((v.u + 0x7FFFu + ((v.u >> 16) & 1u)) >> 16);
}

DEVINL uint32_t pk2bf(float x, float y) {
    __hip_bfloat162 h = __float22bfloat162_rn(float2{x, y});
    union { __hip_bfloat162 h; uint32_t u; } v; v.h = h;
    return v.u;
}

DEVINL floatx4 mfma16(bf16x8 a, bf16x8 b, floatx4 c) {
    return __builtin_amdgcn_mfma_f32_16x16x32_bf16(a, b, c, 0, 0, 0);
}

// async global->LDS DMA, 16B per lane. LDS dest must be base + lane*16 contiguous.
#define GLDS16(g, l)                                                            \
    __builtin_amdgcn_global_load_lds(                                           \
        (const __attribute__((address_space(1))) void*)(g),                     \
        (__attribute__((address_space(3))) void*)(l), 16, 0, 0)

// ---- problem constants ----
constexpr int B_ = 2, S_ = 2048, D_ = 1024, H_ = 16, DK_ = 64;
constexpr int BSROWS = B_ * S_;  // 4096
constexpr int NQB = S_ / 128;    // 16 q-blocks
constexpr int NKT = S_ / 64;     // 32 k-tiles

// per-tile mask flags (1 = all-nonzero tile -> fast path). Rewritten every call.
__device__ int g_flags[B_ * NQB * NKT];

// ================= prep: fp32->bf16 conversion + mask flags ==================
__global__ __launch_bounds__(256)
void prep(const float* __restrict__ q, const float* __restrict__ k,
          const float* __restrict__ v,
          const float* __restrict__ Wq, const float* __restrict__ Wk,
          const float* __restrict__ Wv, const float* __restrict__ Wo,
          unsigned short* __restrict__ qb, unsigned short* __restrict__ kb,
          unsigned short* __restrict__ vb,
          unsigned short* __restrict__ wqb, unsigned short* __restrict__ wkb,
          unsigned short* __restrict__ wvb, unsigned short* __restrict__ wob,
          const int* __restrict__ mask)
{
    __shared__ int f;
    int bid = blockIdx.x;
    if (bid < 8192) {
        const float* src; unsigned short* dst; int rb;
        if      (bid < 2048) { src = q;  dst = qb;  rb = bid; }
        else if (bid < 4096) { src = k;  dst = kb;  rb = bid - 2048; }
        else if (bid < 6144) { src = v;  dst = vb;  rb = bid - 4096; }
        else if (bid < 6656) { src = Wq; dst = wqb; rb = bid - 6144; }
        else if (bid < 7168) { src = Wk; dst = wkb; rb = bid - 6656; }
        else if (bid < 7680) { src = Wv; dst = wvb; rb = bid - 7168; }
        else                 { src = Wo; dst = wob; rb = bid - 7680; }
        size_t e = ((size_t)rb * 256 + threadIdx.x) * 8;
        float4 v0 = *(const float4*)(src + e);
        float4 v1 = *(const float4*)(src + e + 4);
        uint4 o;
        o.x = pk2bf(v0.x, v0.y); o.y = pk2bf(v0.z, v0.w);
        o.z = pk2bf(v1.x, v1.y); o.w = pk2bf(v1.z, v1.w);
        *(uint4*)(dst + e) = o;
    } else {
        int mb = bid - 8192;                  // (b*16 + qb)*32 + kt
        int kt = mb & 31, qq = (mb >> 5) & 15, b = mb >> 9;
        const int* base = mask + (size_t)(b * S_ + qq * 128) * S_ + kt * 64;
        int ok = 1;
        #pragma unroll
        for (int i = 0; i < 8; ++i) {
            int u = threadIdx.x + 256 * i;
            int row = u >> 4, c = u & 15;
            int4 m = *(const int4*)(base + (size_t)row * S_ + c * 4);
            if ((m.x == 0) | (m.y == 0) | (m.z == 0) | (m.w == 0)) ok = 0;
        }
        if (threadIdx.x == 0) f = 1;
        __syncthreads();
        if (!ok) f = 0;
        __syncthreads();
        if (threadIdx.x == 0) g_flags[mb] = f;
    }
}

// ================= fused QKV projection GEMM — DMA-staged ====================
// (unchanged from round 5 — verified) single-barrier double-buffered
// global_load_lds core, XCD-clustered grid, frag-tiled K/V epilogues.
__global__ __launch_bounds__(256)
void gemm_qkv(const unsigned short* __restrict__ qb, const unsigned short* __restrict__ kb,
              const unsigned short* __restrict__ vb,
              const unsigned short* __restrict__ wqb, const unsigned short* __restrict__ wkb,
              const unsigned short* __restrict__ wvb,
              const float* __restrict__ bq, const float* __restrict__ bk,
              const float* __restrict__ bv,
              unsigned short* __restrict__ Qp, unsigned short* __restrict__ KpF,
              unsigned short* __restrict__ VpF)
{
    constexpr int K = D_, N = D_;
    __shared__ unsigned short As[2][128 * 64];
    __shared__ unsigned short Wss[2][64 * 64];

    const int bid = blockIdx.x;                 // 0..1535
    const int xcd = bid & 7, sl = bid >> 3;     // sl 0..191
    const int z = sl >> 6, rr = sl & 63;
    const int nb = rr >> 2, mloc = rr & 3;
    const int m0 = (mloc * 8 + xcd) * 128, n0 = nb * 64;

    const unsigned short* A = z == 0 ? qb  : z == 1 ? kb  : vb;
    const unsigned short* W = z == 0 ? wqb : z == 1 ? wkb : wvb;
    const float* bias       = z == 0 ? bq  : z == 1 ? bk  : bv;

    const int tid  = threadIdx.x;
    const int lane = tid & 63, wave = tid >> 6;
    const int lr = lane & 15, lg = lane >> 4;
    const int wm = (wave >> 1) * 64, wn = (wave & 1) * 32;

    int rowA[4], kcA[4], rowW[2], kcW[2];
    #pragma unroll
    for (int j = 0; j < 4; ++j) {
        int L = (wave * 4 + j) * 64 + lane;
        rowA[j] = L >> 3; kcA[j] = (L & 7) ^ (rowA[j] & 7);
    }
    #pragma unroll
    for (int j = 0; j < 2; ++j) {
        int L = (wave * 2 + j) * 64 + lane;
        rowW[j] = L >> 3; kcW[j] = (L & 7) ^ (rowW[j] & 7);
    }

    auto dma = [&](int k0, int buf) {
        #pragma unroll
        for (int j = 0; j < 4; ++j)
            GLDS16(A + (size_t)(m0 + rowA[j]) * K + k0 + kcA[j] * 8,
                   &As[buf][(wave * 4 + j) * 512 + lane * 8]);
        #pragma unroll
        for (int j = 0; j < 2; ++j)
            GLDS16(W + (size_t)(n0 + rowW[j]) * K + k0 + kcW[j] * 8,
                   &Wss[buf][(wave * 2 + j) * 512 + lane * 8]);
    };

    floatx4 acc[4][2];
    #pragma unroll
    for (int mt = 0; mt < 4; ++mt)
        #pragma unroll
        for (int nt = 0; nt < 2; ++nt)
            acc[mt][nt] = floatx4{0.f, 0.f, 0.f, 0.f};

    dma(0, 0);
    for (int it = 0; it < K / 64; ++it) {
        __syncthreads();
        if (it + 1 < K / 64) dma((it + 1) * 64, (it + 1) & 1);
        const int buf = it & 1;

        #pragma unroll
        for (int kf = 0; kf < 2; ++kf) {
            bf16x8 af[4], bfr[2];
            #pragma unroll
            for (int mt = 0; mt < 4; ++mt) {
                int row = wm + mt * 16 + lr;
                af[mt] = *(const bf16x8*)&As[buf][row * 64 + (((kf * 4 + lg) ^ (lr & 7)) * 8)];
            }
            #pragma unroll
            for (int nt = 0; nt < 2; ++nt) {
                int row = wn + nt * 16 + lr;
                bfr[nt] = *(const bf16x8*)&Wss[buf][row * 64 + (((kf * 4 + lg) ^ (lr & 7)) * 8)];
            }
            #pragma unroll
            for (int mt = 0; mt < 4; ++mt)
                #pragma unroll
                for (int nt = 0; nt < 2; ++nt)
                    acc[mt][nt] = mfma16(af[mt], bfr[nt], acc[mt][nt]);
        }
    }

    if (z == 0) {
        #pragma unroll
        for (int nt = 0; nt < 2; ++nt) {
            int col = n0 + wn + nt * 16 + lr;
            float bv2 = bias[col];
            #pragma unroll
            for (int mt = 0; mt < 4; ++mt)
                #pragma unroll
                for (int reg = 0; reg < 4; ++reg) {
                    int row = m0 + wm + mt * 16 + lg * 4 + reg;
                    Qp[(size_t)row * N + col] = f2bf((acc[mt][nt][reg] + bv2) * 0.125f);
                }
        }
    } else if (z == 1) {
        #pragma unroll
        for (int nt = 0; nt < 2; ++nt) {
            int c = n0 + wn + nt * 16 + lr;
            int h = c >> 6, d = c & 63;
            int kfA = d >> 5, lgA = (d >> 3) & 3, j = d & 7;
            float bv2 = bias[c];
            #pragma unroll
            for (int mt = 0; mt < 4; ++mt)
                #pragma unroll
                for (int reg = 0; reg < 4; ++reg) {
                    int t = m0 + wm + mt * 16 + lg * 4 + reg;
                    int bb = t >> 11, sx = t & (S_ - 1);
                    int kt = sx >> 6, key = sx & 63;
                    int mtA = key >> 4, lrA = key & 15;
                    size_t off = (((size_t)(bb * 16 + h) * 32 + kt) * 8 + (kfA * 4 + mtA)) * 512
                               + (lrA + 16 * lgA) * 8 + j;
                    KpF[off] = f2bf(acc[mt][nt][reg] + bv2);
                }
        }
    } else {
        #pragma unroll
        for (int nt = 0; nt < 2; ++nt) {
            int c = n0 + wn + nt * 16 + lr;
            int h = c >> 6, dtA = (c >> 4) & 3;   // lrA == lr
            float bv2 = bias[c];
            #pragma unroll
            for (int mt = 0; mt < 4; ++mt) {
                int t0 = m0 + wm + mt * 16 + lg * 4;
                int bb = t0 >> 11, s0 = t0 & (S_ - 1);
                int kt = s0 >> 6, key = s0 & 63;
                int kfA = key >> 5, lgA = (key >> 3) & 3, j0 = key & 7;
                size_t off = (((size_t)(bb * 16 + h) * 32 + kt) * 8 + (dtA * 2 + kfA)) * 512
                           + (lr + 16 * lgA) * 8 + j0;
                uint2 p;
                p.x = pk2bf(acc[mt][nt][0] + bv2, acc[mt][nt][1] + bv2);
                p.y = pk2bf(acc[mt][nt][2] + bv2, acc[mt][nt][3] + bv2);
                *(uint2*)&VpF[off] = p;
            }
        }
    }
}

// ================= Flash attention: zero-barrier + K-prefetch pipeline =======
// Round-6: software-pipelined K loads (double-buffered kA/kB register sets,
// unroll-by-2 so no register rotation movs); V(kt) loads issue at body top so
// their latency hides under QK+softmax (~600 cyc); all 32 mask flags pre-read
// into SGPRs. Everything else identical to verified round-5 kernel.
__global__ __launch_bounds__(256, 2)
void attn_flash(const unsigned short* __restrict__ Qp,
                const unsigned short* __restrict__ KpF,
                const unsigned short* __restrict__ VpF,
                const int* __restrict__ mask,
                unsigned short* __restrict__ Out)
{
    constexpr int LD = 72;
    __shared__ unsigned short Ps[128 * LD];

    const int tid = threadIdx.x;
    const int lane = tid & 63, wave = tid >> 6;
    const int lr = lane & 15, lg = lane >> 4;
    const int h = blockIdx.x, qb = blockIdx.y, b = blockIdx.z;
    const int q0 = qb * 128, qw = q0 + wave * 32;

    bf16x8 qf[2][2];
    #pragma unroll
    for (int qt = 0; qt < 2; ++qt)
        #pragma unroll
        for (int kf = 0; kf < 2; ++kf)
            qf[qt][kf] = *(const bf16x8*)(Qp + (size_t)(b * S_ + qw + qt * 16 + lr) * D_ +
                                          h * DK_ + kf * 32 + lg * 8);

    float l_[2] = {0.f, 0.f};
    floatx4 o_acc[2][4];
    #pragma unroll
    for (int qt = 0; qt < 2; ++qt)
        #pragma unroll
        for (int dt = 0; dt < 4; ++dt) o_acc[qt][dt] = floatx4{0.f, 0.f, 0.f, 0.f};

    const unsigned short* kbase = KpF + (size_t)(b * 16 + h) * 32 * 4096 + lane * 8;
    const unsigned short* vbase = VpF + (size_t)(b * 16 + h) * 32 * 4096 + lane * 8;
    const int fbase = (b * NQB + qb) * NKT;
    unsigned short* PsW = &Ps[(wave * 32 + lr) * LD];

    // all 32 per-tile flags -> SGPRs (uniform loads), zero in-loop latency
    int flgall[NKT];
    #pragma unroll
    for (int i = 0; i < NKT; ++i) flgall[i] = g_flags[fbase + i];

    auto loadK = [&](bf16x8* dst, int kt) {
        const unsigned short* p = kbase + kt * 4096;
        #pragma unroll
        for (int c = 0; c < 8; ++c) dst[c] = *(const bf16x8*)(p + c * 512);
    };

    bf16x8 kA[8], kB[8], vf[8];
    loadK(kA, 0);

    auto step = [&](int kt, bf16x8* cur, bf16x8* nxt) {
        // V(kt): issue now, consumed ~600 cyc later by PV
        const unsigned short* vbp = vbase + kt * 4096;
        #pragma unroll
        for (int c = 0; c < 8; ++c) vf[c] = *(const bf16x8*)(vbp + c * 512);

        // ---- S^T = K * Q^T (consumes cur = K(kt), prefetched last iter) ----
        floatx4 sc[2][4];
        #pragma unroll
        for (int qt = 0; qt < 2; ++qt)
            #pragma unroll
            for (int mt = 0; mt < 4; ++mt) sc[qt][mt] = floatx4{0.f, 0.f, 0.f, 0.f};
        #pragma unroll
        for (int mt = 0; mt < 4; ++mt)
            #pragma unroll
            for (int kf = 0; kf < 2; ++kf)
                #pragma unroll
                for (int qt = 0; qt < 2; ++qt)
                    sc[qt][mt] = mfma16(cur[kf * 4 + mt], qf[qt][kf], sc[qt][mt]);

        // ---- prefetch K(kt+1): full body to cover ----
        int ktn = kt + 1 < NKT ? kt + 1 : 0;
        loadK(nxt, ktn);

        if (flgall[kt] == 0) {
            #pragma unroll
            for (int qt = 0; qt < 2; ++qt) {
                int qq = qw + qt * 16 + lr;
                const int* mrow = mask + (size_t)(b * S_ + qq) * S_ + kt * 64;
                #pragma unroll
                for (int mt = 0; mt < 4; ++mt)
                    #pragma unroll
                    for (int reg = 0; reg < 4; ++reg)
                        if (mrow[mt * 16 + lg * 4 + reg] == 0)
                            sc[qt][mt][reg] = -1e9f;
            }
        }

        // ---- exp (fixed max), per-lane l partial, P -> wave-private LDS ----
        #pragma unroll
        for (int qt = 0; qt < 2; ++qt) {
            #pragma unroll
            for (int mt = 0; mt < 4; ++mt) {
                float p0 = __expf(sc[qt][mt][0]), p1 = __expf(sc[qt][mt][1]);
                float p2 = __expf(sc[qt][mt][2]), p3 = __expf(sc[qt][mt][3]);
                l_[qt] += (p0 + p1) + (p2 + p3);
                uint2 pk; pk.x = pk2bf(p0, p1); pk.y = pk2bf(p2, p3);
                *(uint2*)&PsW[qt * 16 * LD + mt * 16 + lg * 4] = pk;
            }
        }

        // ---- O^T += V^T * P^T ----
        bf16x8 pb[2][2];
        #pragma unroll
        for (int qt = 0; qt < 2; ++qt)
            #pragma unroll
            for (int kf = 0; kf < 2; ++kf)
                pb[qt][kf] = *(const bf16x8*)&PsW[qt * 16 * LD + kf * 32 + lg * 8];
        #pragma unroll
        for (int dt = 0; dt < 4; ++dt)
            #pragma unroll
            for (int kf = 0; kf < 2; ++kf)
                #pragma unroll
                for (int qt = 0; qt < 2; ++qt)
                    o_acc[qt][dt] = mfma16(vf[dt * 2 + kf], pb[qt][kf], o_acc[qt][dt]);
    };

    for (int kt = 0; kt < NKT; kt += 2) {
        step(kt, kA, kB);
        step(kt + 1, kB, kA);
    }

    #pragma unroll
    for (int qt = 0; qt < 2; ++qt) {
        float l = l_[qt];
        l += __shfl_xor(l, 16, 64);
        l += __shfl_xor(l, 32, 64);
        float inv = 1.f / l;
        int qq = qw + qt * 16 + lr;
        #pragma unroll
        for (int dt = 0; dt < 4; ++dt) {
            uint2 p;
            p.x = pk2bf(o_acc[qt][dt][0] * inv, o_acc[qt][dt][1] * inv);
            p.y = pk2bf(o_acc[qt][dt][2] * inv, o_acc[qt][dt][3] * inv);
            *(uint2*)&Out[(size_t)(b * S_ + qq) * D_ + h * DK_ + dt * 16 + lg * 4] = p;
        }
    }
}

// ================= output GEMM: DMA-staged + XCD-clustered swizzle ===========
__global__ __launch_bounds__(256)
void gemm_out(const unsigned short* __restrict__ Ap,
              const unsigned short* __restrict__ Wb,
              const float* __restrict__ bias, float* __restrict__ Cptr)
{
    constexpr int K = D_, N = D_;
    __shared__ unsigned short As[2][128 * 64];
    __shared__ unsigned short Wss[2][64 * 64];

    const int bid = blockIdx.x;                 // 0..511
    const int xcd = bid & 7, sl = bid >> 3;     // sl 0..63
    const int nb = sl >> 2, mloc = sl & 3;
    const int m0 = (mloc * 8 + xcd) * 128, n0 = nb * 64;

    const int tid  = threadIdx.x;
    const int lane = tid & 63, wave = tid >> 6;
    const int lr = lane & 15, lg = lane >> 4;
    const int wm = (wave >> 1) * 64, wn = (wave & 1) * 32;

    int rowA[4], kcA[4], rowW[2], kcW[2];
    #pragma unroll
    for (int j = 0; j < 4; ++j) {
        int L = (wave * 4 + j) * 64 + lane;
        rowA[j] = L >> 3; kcA[j] = (L & 7) ^ (rowA[j] & 7);
    }
    #pragma unroll
    for (int j = 0; j < 2; ++j) {
        int L = (wave * 2 + j) * 64 + lane;
        rowW[j] = L >> 3; kcW[j] = (L & 7) ^ (rowW[j] & 7);
    }

    auto dma = [&](int k0, int buf) {
        #pragma unroll
        for (int j = 0; j < 4; ++j)
            GLDS16(Ap + (size_t)(m0 + rowA[j]) * K + k0 + kcA[j] * 8,
                   &As[buf][(wave * 4 + j) * 512 + lane * 8]);
        #pragma unroll
        for (int j = 0; j < 2; ++j)
            GLDS16(Wb + (size_t)(n0 + rowW[j]) * K + k0 + kcW[j] * 8,
                   &Wss[buf][(wave * 2 + j) * 512 + lane * 8]);
    };

    floatx4 acc[4][2];
    #pragma unroll
    for (int mt = 0; mt < 4; ++mt)
        #pragma unroll
        for (int nt = 0; nt < 2; ++nt)
            acc[mt][nt] = floatx4{0.f, 0.f, 0.f, 0.f};

    dma(0, 0);
    for (int it = 0; it < K / 64; ++it) {
        __syncthreads();
        if (it + 1 < K / 64) dma((it + 1) * 64, (it + 1) & 1);
        const int buf = it & 1;

        #pragma unroll
        for (int kf = 0; kf < 2; ++kf) {
            bf16x8 af[4], bfr[2];
            #pragma unroll
            for (int mt = 0; mt < 4; ++mt) {
                int row = wm + mt * 16 + lr;
                af[mt] = *(const bf16x8*)&As[buf][row * 64 + (((kf * 4 + lg) ^ (lr & 7)) * 8)];
            }
            #pragma unroll
            for (int nt = 0; nt < 2; ++nt) {
                int row = wn + nt * 16 + lr;
                bfr[nt] = *(const bf16x8*)&Wss[buf][row * 64 + (((kf * 4 + lg) ^ (lr & 7)) * 8)];
            }
            #pragma unroll
            for (int mt = 0; mt < 4; ++mt)
                #pragma unroll
                for (int nt = 0; nt < 2; ++nt)
                    acc[mt][nt] = mfma16(af[mt], bfr[nt], acc[mt][nt]);
        }
    }

    #pragma unroll
    for (int nt = 0; nt < 2; ++nt) {
        int col = n0 + wn + nt * 16 + lr;
        float bv2 = bias[col];
        #pragma unroll
        for (int mt = 0; mt < 4; ++mt)
            #pragma unroll
            for (int reg = 0; reg < 4; ++reg) {
                int row = m0 + wm + mt * 16 + lg * 4 + reg;
                Cptr[(size_t)row * N + col] = acc[mt][nt][reg] + bv2;
            }
    }
}

// ================= launch ====================================================
extern "C" void kernel_launch(void* const* d_in, const int* in_sizes, int n_in,
                              void* d_out, int out_size, void* d_ws, size_t ws_size,
                              hipStream_t stream)
{
    const float* query = (const float*)d_in[0];
    const float* key   = (const float*)d_in[1];
    const float* value = (const float*)d_in[2];
    const int*   mask  = (const int*)d_in[3];
    const float* Wq = (const float*)d_in[4];
    const float* bq = (const float*)d_in[5];
    const float* Wk = (const float*)d_in[6];
    const float* bk = (const float*)d_in[7];
    const float* Wv = (const float*)d_in[8];
    const float* bv = (const float*)d_in[9];
    const float* Wo = (const float*)d_in[10];
    const float* bo = (const float*)d_in[11];

    // ws (56 MB): qb kb vb (8 MB ea) | wqb wkb wvb wob (2 MB ea) |
    //             Qp KpF VpF (8 MB ea) | Ap aliases qb (dead after gemm_qkv)
    unsigned short* qb  = (unsigned short*)d_ws;
    unsigned short* kb  = qb  + (size_t)BSROWS * D_;
    unsigned short* vb  = kb  + (size_t)BSROWS * D_;
    unsigned short* wqb = vb  + (size_t)BSROWS * D_;
    unsigned short* wkb = wqb + (size_t)D_ * D_;
    unsigned short* wvb = wkb + (size_t)D_ * D_;
    unsigned short* wob = wvb + (size_t)D_ * D_;
    unsigned short* Qp  = wob + (size_t)D_ * D_;
    unsigned short* KpF = Qp  + (size_t)BSROWS * D_;
    unsigned short* VpF = KpF + (size_t)BSROWS * D_;
    unsigned short* Ap  = qb;   // alias: qb consumed by gemm_qkv before attn writes

    dim3 blk(256);

    hipLaunchKernelGGL(prep, dim3(8192 + 1024), blk, 0, stream,
                       query, key, value, Wq, Wk, Wv, Wo,
                       qb, kb, vb, wqb, wkb, wvb, wob, mask);

    hipLaunchKernelGGL(gemm_qkv, dim3(1536), blk, 0, stream,
                       qb, kb, vb, wqb, wkb, wvb, bq, bk, bv, Qp, KpF, VpF);

    dim3 gattn(H_, NQB, B_);               // (16, 16, 2): id%8 == h%8 (XCD L2)
    hipLaunchKernelGGL(attn_flash, gattn, blk, 0, stream, Qp, KpF, VpF, mask, Ap);

    hipLaunchKernelGGL(gemm_out, dim3(512), blk, 0, stream, Ap, wob, bo, (float*)d_out);
}

// Round 7
// 268.271 us; speedup vs baseline: 1.0409x; 1.0409x over previous
//
#include <hip/hip_runtime.h>
#include <hip/hip_bf16.h>
#include <cstdint>
#include <cmath>

#define DEVINL static __device__ __forceinline__

typedef __attribute__((ext_vector_type(4))) float floatx4;
typedef __attribute__((ext_vector_type(8))) short bf16x8;

#if __has_builtin(__builtin_amdgcn_exp2f)
#define EXP2(x) __builtin_amdgcn_exp2f(x)
#else
#define EXP2(x) exp2f(x)
#endif

DEVINL unsigned short f2bf(float f) {
    union { float f; uint32_t u; } v; v.f = f;
    return (unsigned short)((v.u + 0x7FFFu + ((v.u >> 16) & 1u)) >> 16);
}

DEVINL uint32_t pk2bf(float x, float y) {
    __hip_bfloat162 h = __float22bfloat162_rn(float2{x, y});
    union { __hip_bfloat162 h; uint32_t u; } v; v.h = h;
    return v.u;
}

DEVINL floatx4 mfma16(bf16x8 a, bf16x8 b, floatx4 c) {
    return __builtin_amdgcn_mfma_f32_16x16x32_bf16(a, b, c, 0, 0, 0);
}

// async global->LDS DMA, 16B per lane. LDS dest must be base + lane*16 contiguous.
#define GLDS16(g, l)                                                            \
    __builtin_amdgcn_global_load_lds(                                           \
        (const __attribute__((address_space(1))) void*)(g),                     \
        (__attribute__((address_space(3))) void*)(l), 16, 0, 0)

// ---- problem constants ----
constexpr int B_ = 2, S_ = 2048, D_ = 1024, H_ = 16, DK_ = 64;
constexpr int BSROWS = B_ * S_;  // 4096
constexpr int NQB = S_ / 128;    // 16 q-blocks (flag granularity)
constexpr int NKT = S_ / 64;     // 32 k-tiles
// Q scale: 1/sqrt(64) * log2(e) -- attn exp computed as exp2
constexpr float QSCALE = 0.18033688011112042f;

// per-tile mask flags (1 = all-nonzero tile -> fast path). Rewritten every call.
__device__ int g_flags[B_ * NQB * NKT];

// ================= prep: fp32->bf16 conversion + mask flags ==================
__global__ __launch_bounds__(256)
void prep(const float* __restrict__ q, const float* __restrict__ k,
          const float* __restrict__ v,
          const float* __restrict__ Wq, const float* __restrict__ Wk,
          const float* __restrict__ Wv, const float* __restrict__ Wo,
          unsigned short* __restrict__ qb, unsigned short* __restrict__ kb,
          unsigned short* __restrict__ vb,
          unsigned short* __restrict__ wqb, unsigned short* __restrict__ wkb,
          unsigned short* __restrict__ wvb, unsigned short* __restrict__ wob,
          const int* __restrict__ mask)
{
    __shared__ int f;
    int bid = blockIdx.x;
    if (bid < 8192) {
        const float* src; unsigned short* dst; int rb;
        if      (bid < 2048) { src = q;  dst = qb;  rb = bid; }
        else if (bid < 4096) { src = k;  dst = kb;  rb = bid - 2048; }
        else if (bid < 6144) { src = v;  dst = vb;  rb = bid - 4096; }
        else if (bid < 6656) { src = Wq; dst = wqb; rb = bid - 6144; }
        else if (bid < 7168) { src = Wk; dst = wkb; rb = bid - 6656; }
        else if (bid < 7680) { src = Wv; dst = wvb; rb = bid - 7168; }
        else                 { src = Wo; dst = wob; rb = bid - 7680; }
        size_t e = ((size_t)rb * 256 + threadIdx.x) * 8;
        float4 v0 = *(const float4*)(src + e);
        float4 v1 = *(const float4*)(src + e + 4);
        uint4 o;
        o.x = pk2bf(v0.x, v0.y); o.y = pk2bf(v0.z, v0.w);
        o.z = pk2bf(v1.x, v1.y); o.w = pk2bf(v1.z, v1.w);
        *(uint4*)(dst + e) = o;
    } else {
        int mb = bid - 8192;                  // (b*16 + qb)*32 + kt
        int kt = mb & 31, qq = (mb >> 5) & 15, b = mb >> 9;
        const int* base = mask + (size_t)(b * S_ + qq * 128) * S_ + kt * 64;
        int ok = 1;
        #pragma unroll
        for (int i = 0; i < 8; ++i) {
            int u = threadIdx.x + 256 * i;
            int row = u >> 4, c = u & 15;
            int4 m = *(const int4*)(base + (size_t)row * S_ + c * 4);
            if ((m.x == 0) | (m.y == 0) | (m.z == 0) | (m.w == 0)) ok = 0;
        }
        if (threadIdx.x == 0) f = 1;
        __syncthreads();
        if (!ok) f = 0;
        __syncthreads();
        if (threadIdx.x == 0) g_flags[mb] = f;
    }
}

// ================= fused QKV projection GEMM — DMA-staged ====================
// (verified round-5 core) single-barrier double-buffered global_load_lds,
// XCD-clustered grid, frag-tiled K/V epilogues. Q scale now folds log2(e).
__global__ __launch_bounds__(256)
void gemm_qkv(const unsigned short* __restrict__ qb, const unsigned short* __restrict__ kb,
              const unsigned short* __restrict__ vb,
              const unsigned short* __restrict__ wqb, const unsigned short* __restrict__ wkb,
              const unsigned short* __restrict__ wvb,
              const float* __restrict__ bq, const float* __restrict__ bk,
              const float* __restrict__ bv,
              unsigned short* __restrict__ Qp, unsigned short* __restrict__ KpF,
              unsigned short* __restrict__ VpF)
{
    constexpr int K = D_, N = D_;
    __shared__ unsigned short As[2][128 * 64];
    __shared__ unsigned short Wss[2][64 * 64];

    const int bid = blockIdx.x;                 // 0..1535
    const int xcd = bid & 7, sl = bid >> 3;     // sl 0..191
    const int z = sl >> 6, rr = sl & 63;
    const int nb = rr >> 2, mloc = rr & 3;
    const int m0 = (mloc * 8 + xcd) * 128, n0 = nb * 64;

    const unsigned short* A = z == 0 ? qb  : z == 1 ? kb  : vb;
    const unsigned short* W = z == 0 ? wqb : z == 1 ? wkb : wvb;
    const float* bias       = z == 0 ? bq  : z == 1 ? bk  : bv;

    const int tid  = threadIdx.x;
    const int lane = tid & 63, wave = tid >> 6;
    const int lr = lane & 15, lg = lane >> 4;
    const int wm = (wave >> 1) * 64, wn = (wave & 1) * 32;

    int rowA[4], kcA[4], rowW[2], kcW[2];
    #pragma unroll
    for (int j = 0; j < 4; ++j) {
        int L = (wave * 4 + j) * 64 + lane;
        rowA[j] = L >> 3; kcA[j] = (L & 7) ^ (rowA[j] & 7);
    }
    #pragma unroll
    for (int j = 0; j < 2; ++j) {
        int L = (wave * 2 + j) * 64 + lane;
        rowW[j] = L >> 3; kcW[j] = (L & 7) ^ (rowW[j] & 7);
    }

    auto dma = [&](int k0, int buf) {
        #pragma unroll
        for (int j = 0; j < 4; ++j)
            GLDS16(A + (size_t)(m0 + rowA[j]) * K + k0 + kcA[j] * 8,
                   &As[buf][(wave * 4 + j) * 512 + lane * 8]);
        #pragma unroll
        for (int j = 0; j < 2; ++j)
            GLDS16(W + (size_t)(n0 + rowW[j]) * K + k0 + kcW[j] * 8,
                   &Wss[buf][(wave * 2 + j) * 512 + lane * 8]);
    };

    floatx4 acc[4][2];
    #pragma unroll
    for (int mt = 0; mt < 4; ++mt)
        #pragma unroll
        for (int nt = 0; nt < 2; ++nt)
            acc[mt][nt] = floatx4{0.f, 0.f, 0.f, 0.f};

    dma(0, 0);
    for (int it = 0; it < K / 64; ++it) {
        __syncthreads();
        if (it + 1 < K / 64) dma((it + 1) * 64, (it + 1) & 1);
        const int buf = it & 1;

        #pragma unroll
        for (int kf = 0; kf < 2; ++kf) {
            bf16x8 af[4], bfr[2];
            #pragma unroll
            for (int mt = 0; mt < 4; ++mt) {
                int row = wm + mt * 16 + lr;
                af[mt] = *(const bf16x8*)&As[buf][row * 64 + (((kf * 4 + lg) ^ (lr & 7)) * 8)];
            }
            #pragma unroll
            for (int nt = 0; nt < 2; ++nt) {
                int row = wn + nt * 16 + lr;
                bfr[nt] = *(const bf16x8*)&Wss[buf][row * 64 + (((kf * 4 + lg) ^ (lr & 7)) * 8)];
            }
            #pragma unroll
            for (int mt = 0; mt < 4; ++mt)
                #pragma unroll
                for (int nt = 0; nt < 2; ++nt)
                    acc[mt][nt] = mfma16(af[mt], bfr[nt], acc[mt][nt]);
        }
    }

    if (z == 0) {
        #pragma unroll
        for (int nt = 0; nt < 2; ++nt) {
            int col = n0 + wn + nt * 16 + lr;
            float bv2 = bias[col];
            #pragma unroll
            for (int mt = 0; mt < 4; ++mt)
                #pragma unroll
                for (int reg = 0; reg < 4; ++reg) {
                    int row = m0 + wm + mt * 16 + lg * 4 + reg;
                    Qp[(size_t)row * N + col] = f2bf((acc[mt][nt][reg] + bv2) * QSCALE);
                }
        }
    } else if (z == 1) {
        #pragma unroll
        for (int nt = 0; nt < 2; ++nt) {
            int c = n0 + wn + nt * 16 + lr;
            int h = c >> 6, d = c & 63;
            int kfA = d >> 5, lgA = (d >> 3) & 3, j = d & 7;
            float bv2 = bias[c];
            #pragma unroll
            for (int mt = 0; mt < 4; ++mt)
                #pragma unroll
                for (int reg = 0; reg < 4; ++reg) {
                    int t = m0 + wm + mt * 16 + lg * 4 + reg;
                    int bb = t >> 11, sx = t & (S_ - 1);
                    int kt = sx >> 6, key = sx & 63;
                    int mtA = key >> 4, lrA = key & 15;
                    size_t off = (((size_t)(bb * 16 + h) * 32 + kt) * 8 + (kfA * 4 + mtA)) * 512
                               + (lrA + 16 * lgA) * 8 + j;
                    KpF[off] = f2bf(acc[mt][nt][reg] + bv2);
                }
        }
    } else {
        #pragma unroll
        for (int nt = 0; nt < 2; ++nt) {
            int c = n0 + wn + nt * 16 + lr;
            int h = c >> 6, dtA = (c >> 4) & 3;   // lrA == lr
            float bv2 = bias[c];
            #pragma unroll
            for (int mt = 0; mt < 4; ++mt) {
                int t0 = m0 + wm + mt * 16 + lg * 4;
                int bb = t0 >> 11, s0 = t0 & (S_ - 1);
                int kt = s0 >> 6, key = s0 & 63;
                int kfA = key >> 5, lgA = (key >> 3) & 3, j0 = key & 7;
                size_t off = (((size_t)(bb * 16 + h) * 32 + kt) * 8 + (dtA * 2 + kfA)) * 512
                           + (lr + 16 * lgA) * 8 + j0;
                uint2 p;
                p.x = pk2bf(acc[mt][nt][0] + bv2, acc[mt][nt][1] + bv2);
                p.y = pk2bf(acc[mt][nt][2] + bv2, acc[mt][nt][3] + bv2);
                *(uint2*)&VpF[off] = p;
            }
        }
    }
}

// ================= Flash attention: zero-barrier, 64-q blocks (4/CU) =========
// Round-7: revert round-6's register pipeline (it spilled: VGPR 128 + 17 MB
// scratch writes). Instead double TLP: 64 q-rows/block (16/wave) -> grid 1024
// = 4 blocks/CU = 4 waves/SIMD; per-wave state halves (no spill), waves hide
// each other's K/V latency + exp/LDS chain. exp is raw v_exp_f32 (log2e folded
// into Q scale). Structure otherwise identical to verified round-5 kernel.
__global__ __launch_bounds__(256, 4)
void attn_flash(const unsigned short* __restrict__ Qp,
                const unsigned short* __restrict__ KpF,
                const unsigned short* __restrict__ VpF,
                const int* __restrict__ mask,
                unsigned short* __restrict__ Out)
{
    constexpr int LD = 72;
    __shared__ unsigned short Ps[64 * LD];

    const int tid = threadIdx.x;
    const int lane = tid & 63, wave = tid >> 6;
    const int lr = lane & 15, lg = lane >> 4;
    const int h = blockIdx.x, qb64 = blockIdx.y, b = blockIdx.z;
    const int qw = qb64 * 64 + wave * 16;

    bf16x8 qf[2];
    #pragma unroll
    for (int kf = 0; kf < 2; ++kf)
        qf[kf] = *(const bf16x8*)(Qp + (size_t)(b * S_ + qw + lr) * D_ +
                                  h * DK_ + kf * 32 + lg * 8);

    float l_ = 0.f;
    floatx4 o_acc[4];
    #pragma unroll
    for (int dt = 0; dt < 4; ++dt) o_acc[dt] = floatx4{0.f, 0.f, 0.f, 0.f};

    const unsigned short* kbase = KpF + (size_t)(b * 16 + h) * 32 * 4096 + lane * 8;
    const unsigned short* vbase = VpF + (size_t)(b * 16 + h) * 32 * 4096 + lane * 8;
    const int fbase = (b * NQB + (qb64 >> 1)) * NKT;
    unsigned short* PsW = &Ps[(wave * 16 + lr) * LD];

    for (int kt = 0; kt < NKT; ++kt) {
        const unsigned short* kb = kbase + kt * 4096;
        const unsigned short* vb = vbase + kt * 4096;
        bf16x8 kfr[8], vfr[8];
        #pragma unroll
        for (int c = 0; c < 8; ++c) kfr[c] = *(const bf16x8*)(kb + c * 512);
        #pragma unroll
        for (int c = 0; c < 8; ++c) vfr[c] = *(const bf16x8*)(vb + c * 512);

        // ---- S^T = K * Q^T : sc[mt]; row=key(mt*16+lg*4+reg), col=q(lr) ----
        floatx4 sc[4];
        #pragma unroll
        for (int mt = 0; mt < 4; ++mt) sc[mt] = floatx4{0.f, 0.f, 0.f, 0.f};
        #pragma unroll
        for (int mt = 0; mt < 4; ++mt)
            #pragma unroll
            for (int kf = 0; kf < 2; ++kf)
                sc[mt] = mfma16(kfr[kf * 4 + mt], qf[kf], sc[mt]);

        if (g_flags[fbase + kt] == 0) {
            int qq = qw + lr;
            const int* mrow = mask + (size_t)(b * S_ + qq) * S_ + kt * 64;
            #pragma unroll
            for (int mt = 0; mt < 4; ++mt)
                #pragma unroll
                for (int reg = 0; reg < 4; ++reg)
                    if (mrow[mt * 16 + lg * 4 + reg] == 0)
                        sc[mt][reg] = -1e9f;
        }

        // ---- exp2 (scale pre-folded), per-lane l partial, P -> LDS ----
        #pragma unroll
        for (int mt = 0; mt < 4; ++mt) {
            float p0 = EXP2(sc[mt][0]), p1 = EXP2(sc[mt][1]);
            float p2 = EXP2(sc[mt][2]), p3 = EXP2(sc[mt][3]);
            l_ += (p0 + p1) + (p2 + p3);
            uint2 pk; pk.x = pk2bf(p0, p1); pk.y = pk2bf(p2, p3);
            *(uint2*)&PsW[mt * 16 + lg * 4] = pk;
        }

        // ---- O^T += V^T * P^T ----
        bf16x8 pb[2];
        #pragma unroll
        for (int kf = 0; kf < 2; ++kf)
            pb[kf] = *(const bf16x8*)&PsW[kf * 32 + lg * 8];
        #pragma unroll
        for (int dt = 0; dt < 4; ++dt)
            #pragma unroll
            for (int kf = 0; kf < 2; ++kf)
                o_acc[dt] = mfma16(vfr[dt * 2 + kf], pb[kf], o_acc[dt]);
    }

    // ---- final l reduction (q = lr on all 4 lg lanes) + normalize + store ----
    float l = l_;
    l += __shfl_xor(l, 16, 64);
    l += __shfl_xor(l, 32, 64);
    float inv = 1.f / l;
    int qq = qw + lr;
    #pragma unroll
    for (int dt = 0; dt < 4; ++dt) {
        uint2 p;
        p.x = pk2bf(o_acc[dt][0] * inv, o_acc[dt][1] * inv);
        p.y = pk2bf(o_acc[dt][2] * inv, o_acc[dt][3] * inv);
        *(uint2*)&Out[(size_t)(b * S_ + qq) * D_ + h * DK_ + dt * 16 + lg * 4] = p;
    }
}

// ================= output GEMM: DMA-staged + XCD-clustered swizzle ===========
__global__ __launch_bounds__(256)
void gemm_out(const unsigned short* __restrict__ Ap,
              const unsigned short* __restrict__ Wb,
              const float* __restrict__ bias, float* __restrict__ Cptr)
{
    constexpr int K = D_, N = D_;
    __shared__ unsigned short As[2][128 * 64];
    __shared__ unsigned short Wss[2][64 * 64];

    const int bid = blockIdx.x;                 // 0..511
    const int xcd = bid & 7, sl = bid >> 3;     // sl 0..63
    const int nb = sl >> 2, mloc = sl & 3;
    const int m0 = (mloc * 8 + xcd) * 128, n0 = nb * 64;

    const int tid  = threadIdx.x;
    const int lane = tid & 63, wave = tid >> 6;
    const int lr = lane & 15, lg = lane >> 4;
    const int wm = (wave >> 1) * 64, wn = (wave & 1) * 32;

    int rowA[4], kcA[4], rowW[2], kcW[2];
    #pragma unroll
    for (int j = 0; j < 4; ++j) {
        int L = (wave * 4 + j) * 64 + lane;
        rowA[j] = L >> 3; kcA[j] = (L & 7) ^ (rowA[j] & 7);
    }
    #pragma unroll
    for (int j = 0; j < 2; ++j) {
        int L = (wave * 2 + j) * 64 + lane;
        rowW[j] = L >> 3; kcW[j] = (L & 7) ^ (rowW[j] & 7);
    }

    auto dma = [&](int k0, int buf) {
        #pragma unroll
        for (int j = 0; j < 4; ++j)
            GLDS16(Ap + (size_t)(m0 + rowA[j]) * K + k0 + kcA[j] * 8,
                   &As[buf][(wave * 4 + j) * 512 + lane * 8]);
        #pragma unroll
        for (int j = 0; j < 2; ++j)
            GLDS16(Wb + (size_t)(n0 + rowW[j]) * K + k0 + kcW[j] * 8,
                   &Wss[buf][(wave * 2 + j) * 512 + lane * 8]);
    };

    floatx4 acc[4][2];
    #pragma unroll
    for (int mt = 0; mt < 4; ++mt)
        #pragma unroll
        for (int nt = 0; nt < 2; ++nt)
            acc[mt][nt] = floatx4{0.f, 0.f, 0.f, 0.f};

    dma(0, 0);
    for (int it = 0; it < K / 64; ++it) {
        __syncthreads();
        if (it + 1 < K / 64) dma((it + 1) * 64, (it + 1) & 1);
        const int buf = it & 1;

        #pragma unroll
        for (int kf = 0; kf < 2; ++kf) {
            bf16x8 af[4], bfr[2];
            #pragma unroll
            for (int mt = 0; mt < 4; ++mt) {
                int row = wm + mt * 16 + lr;
                af[mt] = *(const bf16x8*)&As[buf][row * 64 + (((kf * 4 + lg) ^ (lr & 7)) * 8)];
            }
            #pragma unroll
            for (int nt = 0; nt < 2; ++nt) {
                int row = wn + nt * 16 + lr;
                bfr[nt] = *(const bf16x8*)&Wss[buf][row * 64 + (((kf * 4 + lg) ^ (lr & 7)) * 8)];
            }
            #pragma unroll
            for (int mt = 0; mt < 4; ++mt)
                #pragma unroll
                for (int nt = 0; nt < 2; ++nt)
                    acc[mt][nt] = mfma16(af[mt], bfr[nt], acc[mt][nt]);
        }
    }

    #pragma unroll
    for (int nt = 0; nt < 2; ++nt) {
        int col = n0 + wn + nt * 16 + lr;
        float bv2 = bias[col];
        #pragma unroll
        for (int mt = 0; mt < 4; ++mt)
            #pragma unroll
            for (int reg = 0; reg < 4; ++reg) {
                int row = m0 + wm + mt * 16 + lg * 4 + reg;
                Cptr[(size_t)row * N + col] = acc[mt][nt][reg] + bv2;
            }
    }
}

// ================= launch ====================================================
extern "C" void kernel_launch(void* const* d_in, const int* in_sizes, int n_in,
                              void* d_out, int out_size, void* d_ws, size_t ws_size,
                              hipStream_t stream)
{
    const float* query = (const float*)d_in[0];
    const float* key   = (const float*)d_in[1];
    const float* value = (const float*)d_in[2];
    const int*   mask  = (const int*)d_in[3];
    const float* Wq = (const float*)d_in[4];
    const float* bq = (const float*)d_in[5];
    const float* Wk = (const float*)d_in[6];
    const float* bk = (const float*)d_in[7];
    const float* Wv = (const float*)d_in[8];
    const float* bv = (const float*)d_in[9];
    const float* Wo = (const float*)d_in[10];
    const float* bo = (const float*)d_in[11];

    // ws (56 MB): qb kb vb (8 MB ea) | wqb wkb wvb wob (2 MB ea) |
    //             Qp KpF VpF (8 MB ea) | Ap aliases qb (dead after gemm_qkv)
    unsigned short* qb  = (unsigned short*)d_ws;
    unsigned short* kb  = qb  + (size_t)BSROWS * D_;
    unsigned short* vb  = kb  + (size_t)BSROWS * D_;
    unsigned short* wqb = vb  + (size_t)BSROWS * D_;
    unsigned short* wkb = wqb + (size_t)D_ * D_;
    unsigned short* wvb = wkb + (size_t)D_ * D_;
    unsigned short* wob = wvb + (size_t)D_ * D_;
    unsigned short* Qp  = wob + (size_t)D_ * D_;
    unsigned short* KpF = Qp  + (size_t)BSROWS * D_;
    unsigned short* VpF = KpF + (size_t)BSROWS * D_;
    unsigned short* Ap  = qb;   // alias: qb consumed by gemm_qkv before attn writes

    dim3 blk(256);

    hipLaunchKernelGGL(prep, dim3(8192 + 1024), blk, 0, stream,
                       query, key, value, Wq, Wk, Wv, Wo,
                       qb, kb, vb, wqb, wkb, wvb, wob, mask);

    hipLaunchKernelGGL(gemm_qkv, dim3(1536), blk, 0, stream,
                       qb, kb, vb, wqb, wkb, wvb, bq, bk, bv, Qp, KpF, VpF);

    dim3 gattn(H_, S_ / 64, B_);           // (16, 32, 2) = 1024: id%8 == h%8
    hipLaunchKernelGGL(attn_flash, gattn, blk, 0, stream, Qp, KpF, VpF, mask, Ap);

    hipLaunchKernelGGL(gemm_out, dim3(512), blk, 0, stream, Ap, wob, bo, (float*)d_out);
}